// Round 3
// baseline (672.170 us; speedup 1.0000x reference)
//
#include <hip/hip_runtime.h>

#define WARMUP 365
#define NSTEP  1825
#define TTOT   2190
#define KER    15

#define EXP2F(v) __builtin_exp2f(v)
#define LOG2F(v) __builtin_log2f(v)

// Load one 15-step block of inputs (3 floats per step) into a register buffer.
// T0 must satisfy T0+14 <= TTOT-1.
#define LOADBLK(BUF, T0)                                                    \
    do {                                                                    \
        _Pragma("unroll")                                                   \
        for (int j_ = 0; j_ < 15; j_++) {                                   \
            const float* p_ = x + ((size_t)((T0) + j_) * G + g) * 3;        \
            BUF[3 * j_ + 0] = p_[0];                                        \
            BUF[3 * j_ + 1] = p_[1];                                        \
            BUF[3 * j_ + 2] = p_[2];                                        \
        }                                                                   \
    } while (0)

// Run 15 HBV steps from BUF; TB is the absolute time of BUF[0].
// Convolution slot for time t is (t-365)%15; all blocks start at t%15==0,
// so slot = (j+10)%15 — a compile-time constant after unrolling.
#define RUNBLK(BUF, TB)                                                     \
    do {                                                                    \
        _Pragma("unroll")                                                   \
        for (int j = 0; j < 15; j++) {                                      \
            const float pcp = BUF[3 * j + 0];                               \
            const float pet = BUF[3 * j + 1];                               \
            const float tmp = BUF[3 * j + 2];                               \
            /* input-only precomputes (off the recurrent chain) */          \
            const float dtemp   = tmp - tt;                                 \
            const float rain    = (tmp >= tt) ? pcp : 0.0f;                 \
            const float snow    = pcp - rain;                               \
            const float meltcap = fmaxf(cfmax * dtemp, 0.0f);               \
            const float refrcap = fmaxf(-cfrx * dtemp, 0.0f);               \
            const float pl      = pet * inv_lpfc;                           \
            /* snow/melt state */                                           \
            sp += snow;                                                     \
            const float melt = fminf(meltcap, sp);                          \
            mw += melt;                                                     \
            sp -= melt;                                                     \
            const float refr = fminf(refrcap, mw);                          \
            sp += refr;                                                     \
            mw -= refr;                                                     \
            const float tosoil = fmaxf(mw - cwh * sp, 0.0f);                \
            mw -= tosoil;                                                   \
            /* soil moisture */                                             \
            const float wet =                                               \
                fminf(EXP2F(beta * LOG2F(sm * inv_fc)), 1.0f);              \
            const float inflow = rain + tosoil;                             \
            const float rech   = inflow * wet;                              \
            const float smx    = sm + inflow;                               \
            sm = smx - rech;                                                \
            const float exc = fmaxf(sm - fc, 0.0f);                         \
            sm = fminf(sm, fc);                                             \
            const float et = fminf(sm, fminf(pl * sm, pet));                \
            sm = fmaxf(sm - et, 1e-5f);                                     \
            /* upper / lower zones */                                       \
            suz += rech + exc;                                              \
            const float perc = fminf(suz, pperc);                           \
            suz -= perc;                                                    \
            const float q0 = k0 * fmaxf(suz - uzl, 0.0f);                   \
            suz -= q0;                                                      \
            const float q1 = k1 * suz;                                      \
            suz -= q1;                                                      \
            slz += perc;                                                    \
            const float q2 = k2 * slz;                                      \
            slz -= q2;                                                      \
            const float q = q0 + q1 + q2;                                   \
            /* fused 15-tap causal conv, distributed accumulators */        \
            if ((TB) + j >= WARMUP) {                                       \
                const int s_ = (j + 10) % 15;                               \
                out[(size_t)((TB) + j - WARMUP) * G + g] =                  \
                    acc[s_] + w[0] * q;                                     \
                acc[s_] = 0.0f;                                             \
                _Pragma("unroll")                                           \
                for (int k = 1; k < 15; k++)                                \
                    acc[(s_ + k) % 15] += w[k] * q;                         \
            }                                                               \
        }                                                                   \
    } while (0)

__global__ __launch_bounds__(64, 1) void hbv_fused_kernel(
    const float* __restrict__ x,       // (TTOT, G, 3): precip, pet, temp
    const float* __restrict__ params,  // (G, 14) in [0,1]
    float* __restrict__ out,           // (NSTEP, G)
    int G)
{
    const int g = blockIdx.x * 64 + threadIdx.x;
    if (g >= G) return;

    // ---- scale parameters ----
    const float* pr = params + (size_t)g * 14;
    const float beta  = 1.0f   + pr[0]  * 5.0f;
    const float fc    = 50.0f  + pr[1]  * 950.0f;
    const float k0    = 0.05f  + pr[2]  * 0.85f;
    const float k1    = 0.01f  + pr[3]  * 0.49f;
    const float k2    = 0.001f + pr[4]  * 0.199f;
    const float lp    = 0.2f   + pr[5]  * 0.8f;
    const float pperc =          pr[6]  * 10.0f;
    const float uzl   =          pr[7]  * 100.0f;
    const float tt    = -2.5f  + pr[8]  * 5.0f;
    const float cfmax = 0.5f   + pr[9]  * 9.5f;
    const float cfr   =          pr[10] * 0.1f;
    const float cwh   =          pr[11] * 0.2f;
    const float ra    =          pr[12] * 2.9f;
    const float rb    =          pr[13] * 6.5f;

    // ---- UH weights: gammaln(aa) and aa*log(theta) cancel under the
    //      normalization, so w[k] ∝ exp2((aa-1)*log2(tk) - tk*log2e/th) ----
    const float aa = fmaxf(ra, 0.0f) + 0.1f;
    const float th = fmaxf(rb, 0.0f) + 0.5f;
    const float c1 = aa - 1.0f;
    const float c2 = 1.4426950408889634f / th;   // log2(e)/theta
    float w[KER];
    float ws = 0.0f;
    #pragma unroll
    for (int k = 0; k < KER; k++) {
        const float tk = 0.5f + (float)k;
        w[k] = EXP2F(c1 * LOG2F(tk) - tk * c2);
        ws += w[k];
    }
    const float inv_ws = 1.0f / ws;
    #pragma unroll
    for (int k = 0; k < KER; k++) w[k] *= inv_ws;

    const float inv_fc   = 1.0f / fc;
    const float inv_lpfc = 1.0f / (lp * fc);
    const float cfrx     = cfr * cfmax;

    // ---- state ----
    float sp  = 0.001f;
    float mw  = 0.001f;
    float sm  = 0.001f;
    float suz = 0.001f;
    float slz = 0.001f;

    // ---- conv accumulators ----
    float acc[KER];
    #pragma unroll
    for (int k = 0; k < KER; k++) acc[k] = 0.0f;

    // ---- pipelined time loop: 73 double-blocks of 2x15 steps, ping-pong
    //      register buffers, prefetch distance = 15 steps ----
    float A[45], B[45];
    LOADBLK(A, 0);
    for (int d = 0; d < 73; ++d) {
        const int t0 = 30 * d;
        LOADBLK(B, t0 + 15);                       // t0+15 <= 2175, in range
        RUNBLK(A, t0);
        const int tn = (t0 + 30 <= TTOT - 15) ? (t0 + 30) : (TTOT - 15);
        LOADBLK(A, tn);                            // clamped (last iter only)
        RUNBLK(B, t0 + 15);
    }
}

extern "C" void kernel_launch(void* const* d_in, const int* in_sizes, int n_in,
                              void* d_out, int out_size, void* d_ws, size_t ws_size,
                              hipStream_t stream) {
    const float* x      = (const float*)d_in[0];   // (2190, G, 3) f32
    const float* params = (const float*)d_in[1];   // (G, 14) f32
    float* out = (float*)d_out;                    // (1825, G, 1) f32
    const int G = in_sizes[1] / 14;
    const int blocks = (G + 63) / 64;
    hbv_fused_kernel<<<blocks, 64, 0, stream>>>(x, params, out, G);
}